// Round 6
// baseline (110.421 us; speedup 1.0000x reference)
//
#include <hip/hip_runtime.h>

// NegativeSelection: score[i] = max(min_j ||x_i - s_j|| - 0.1, 0)
// N=16384, M=8192, D=128, fp32 in/out.
//
// d2 = a2 + b2 - 2*dot. dot via fp16 MFMA (32x32x16), A pre-negated so
// acc = C_init(b2/2) + (-x)·s = b2/2 - dot; min over j tracked per row.
// final: d2 = a2 + 2*min, score = max(sqrt(max(d2,0)) - 0.1, 0).
//
// This revision: BARRIER-FREE min_gemm. Measured plateau (MfmaUtil ~30%
// across three different block-wide-barrier schedules) is the barrier
// convoy, not LDS BW. Fix: each wave owns a 128row x 32col output slice
// and stages its OWN 8 KB B-slice into a PRIVATE LDS double-buffer via
// per-lane-gathered global_load_lds. All hazards wave-local:
//   - s_waitcnt vmcnt(8) waits only this wave's own stage(t);
//   - re-stage of buf[t&1] issues after the MFMAs (lgkm waits guarantee
//     the ds_reads of tile t completed), protected by sched_barrier(0);
//   - NO s_barrier in the loop: waves drift, co-resident waves fill the
//     matrix pipe during each other's load/fold tails.
// 4 waves/block, 72 KB LDS -> 2 blocks/CU. setprio(1) around MFMA
// clusters (waves at independent phases = the regime where it helps).
//
// ws: Aws fp16 [N*128] (4 MB, [k8][row][8], NEGATED), Bws fp16 [M*128] (2 MB),
//     b2h f32 [M], Pmin f32 [N*16], a2 f32 [N]  -> ~7.3 MB.

using half_t = _Float16;
typedef _Float16 half8 __attribute__((ext_vector_type(8)));
typedef _Float16 half2v __attribute__((ext_vector_type(2)));
typedef float floatx16 __attribute__((ext_vector_type(16)));

#define TILE_ELEMS (128 * 128)   // 32 KB fp16

__device__ __forceinline__ void async_load16(const void* g, void* l) {
    __builtin_amdgcn_global_load_lds(
        (const __attribute__((address_space(1))) void*)g,
        (__attribute__((address_space(3))) void*)l, 16, 0, 0);
}

// Stage this wave's 32-col slice (8 KB) of one B tile into its private LDS
// buffer: 8 instructions, per-lane gathered global source, linear LDS dest.
// Slice layout: [k8:16][col31:32][8elems]; instr c covers k8 = 2c..2c+1.
__device__ __forceinline__ void stage_slice(const half_t* __restrict__ Bt,
                                            half_t* __restrict__ dst,
                                            int wc, int lane) {
    int l5 = lane >> 5, l31 = lane & 31;
    #pragma unroll
    for (int c = 0; c < 8; ++c) {
        const half_t* src = Bt + (size_t)((c * 2 + l5) * 128 + wc * 32 + l31) * 8;
        async_load16(src, dst + (size_t)c * 512);
    }
}

__device__ __forceinline__ half2v h2min(half2v a, half2v b) {
    return __builtin_elementwise_min(a, b);   // v_pk_min_f16
}

__device__ __forceinline__ half2v pkrtz(float lo, float hi) {
    auto t = __builtin_amdgcn_cvt_pkrtz(lo, hi);
    return __builtin_bit_cast(half2v, t);
}

// One block per 128x128 tile. fp32 -> fp16 tiled layout [k8][row][8]
// (chunk c = k8*128+row stored at element c*8). A negated.
// B tiles: b2h = 0.5*sum(row^2). A tiles: a2 = sum(row^2).
__global__ __launch_bounds__(256) void prep_kernel(
    const float* __restrict__ x, const float* __restrict__ self,
    half_t* __restrict__ Aws, half_t* __restrict__ Bws,
    float* __restrict__ b2h, float* __restrict__ a2, int Atiles)
{
    __shared__ float part[256];
    int tile = blockIdx.x;
    int tid  = threadIdx.x;
    bool isB = tile >= Atiles;
    int bt   = tile - Atiles;
    const float* src = isB ? (self + (size_t)bt * TILE_ELEMS)
                           : (x    + (size_t)tile * TILE_ELEMS);
    half_t* dst = isB ? (Bws + (size_t)bt * TILE_ELEMS)
                      : (Aws + (size_t)tile * TILE_ELEMS);
    float sgn = isB ? 1.f : -1.f;

    int rowt = tid & 127;
    int k8b  = tid >> 7;
    float ss = 0.f;
    #pragma unroll
    for (int i = 0; i < 8; ++i) {
        int k8 = i * 2 + k8b;
        const float4* p = (const float4*)(src + rowt * 128 + k8 * 8);
        float4 f0 = p[0];
        float4 f1 = p[1];
        half8 h;
        h[0] = (half_t)(sgn * f0.x); h[1] = (half_t)(sgn * f0.y);
        h[2] = (half_t)(sgn * f0.z); h[3] = (half_t)(sgn * f0.w);
        h[4] = (half_t)(sgn * f1.x); h[5] = (half_t)(sgn * f1.y);
        h[6] = (half_t)(sgn * f1.z); h[7] = (half_t)(sgn * f1.w);
        *(half8*)(dst + (size_t)(i * 256 + tid) * 8) = h;
        ss += f0.x*f0.x + f0.y*f0.y + f0.z*f0.z + f0.w*f0.w;
        ss += f1.x*f1.x + f1.y*f1.y + f1.z*f1.z + f1.w*f1.w;
    }
    part[tid] = ss;
    __syncthreads();
    if (tid < 128) {
        float tot = part[tid] + part[tid + 128];
        if (isB) b2h[bt * 128 + tid] = 0.5f * tot;
        else     a2[tile * 128 + tid] = tot;
    }
}

// One barrier-free pipeline iteration. VN = this wave's vmcnt allowance:
// 8 mid-loop (stage(t) drained, stage(t+1)'s 8 still in flight), 0 last.
template<int VN>
__device__ __forceinline__ void gemm_iter(
    int t, int iters, int wc, int lane, int ln31, int lh,
    const half_t* __restrict__ Bbase,
    half_t* __restrict__ buf0, half_t* __restrict__ buf1,
    const float* __restrict__ b2sh,
    const half8 (&areg)[4][8], half2v (&minacc)[4][8])
{
    // Wave-local wait: my stage(t) has landed in my buf[t&1].
    if constexpr (VN == 8) asm volatile("s_waitcnt vmcnt(8)" ::: "memory");
    else                   asm volatile("s_waitcnt vmcnt(0)" ::: "memory");
    __builtin_amdgcn_sched_barrier(0);

    const half_t* Bs = (t & 1) ? buf1 : buf0;
    float b2v = b2sh[t * 128 + wc * 32 + ln31];

    // This wave's 8 B fragments (contiguous b128 reads, conflict-free).
    half8 bf[8];
    #pragma unroll
    for (int ki = 0; ki < 8; ++ki)
        bf[ki] = *(const half8*)(Bs + (size_t)((ki * 2 + lh) * 32 + ln31) * 8);

    floatx16 c0;
    #pragma unroll
    for (int r = 0; r < 16; ++r) c0[r] = b2v;

    __builtin_amdgcn_s_setprio(1);
    #pragma unroll
    for (int rp = 0; rp < 2; ++rp) {
        floatx16 a0 = __builtin_amdgcn_mfma_f32_32x32x16_f16(areg[rp * 2][0],     bf[0], c0, 0, 0, 0);
        floatx16 a1 = __builtin_amdgcn_mfma_f32_32x32x16_f16(areg[rp * 2 + 1][0], bf[0], c0, 0, 0, 0);
        #pragma unroll
        for (int ki = 1; ki < 8; ++ki) {
            a0 = __builtin_amdgcn_mfma_f32_32x32x16_f16(areg[rp * 2][ki],     bf[ki], a0, 0, 0, 0);
            a1 = __builtin_amdgcn_mfma_f32_32x32x16_f16(areg[rp * 2 + 1][ki], bf[ki], a1, 0, 0, 0);
        }
        #pragma unroll
        for (int i = 0; i < 8; ++i) {
            minacc[rp * 2][i]     = h2min(minacc[rp * 2][i],     pkrtz(a0[2 * i], a0[2 * i + 1]));
            minacc[rp * 2 + 1][i] = h2min(minacc[rp * 2 + 1][i], pkrtz(a1[2 * i], a1[2 * i + 1]));
        }
    }
    __builtin_amdgcn_s_setprio(0);

    // Re-stage buf[t&1] with tile t+2. Pinned AFTER the MFMAs (whose lgkm
    // waits guarantee tile t's ds_reads completed) by sched_barrier(0).
    __builtin_amdgcn_sched_barrier(0);
    if (t + 2 < iters)
        stage_slice(Bbase + (size_t)(t + 2) * TILE_ELEMS,
                    (t & 1) ? buf1 : buf0, wc, lane);
}

// Grid: (N/128, 4 M-slices), 256 threads = 4 waves. Wave wc owns the full
// 128 rows x cols wc*32..+32. Private double-buffered B slices; no barrier
// in the main loop. LDS 72 KB -> 2 blocks/CU.
__global__ __launch_bounds__(256, 2) void min_gemm_kernel(
    const half_t* __restrict__ Aws, const half_t* __restrict__ Bws,
    const float* __restrict__ b2h, float* __restrict__ Pmin, int Mslice)
{
    __shared__ half_t slices[4][2][4096];   // 64 KB: [wave][buf][8 KB]
    __shared__ float  b2sh[2048];           // 8 KB (Mslice = 2048)

    int tid  = threadIdx.x;
    int lane = tid & 63;
    int wc   = tid >> 6;          // 0..3 : this wave's 32-col group
    int ln31 = lane & 31, lh = lane >> 5;

    // A fragments: rows rt*32 + ln31, full K, in regs (128 VGPR).
    const half_t* Atile = Aws + (size_t)blockIdx.x * TILE_ELEMS;
    half8 areg[4][8];
    #pragma unroll
    for (int rt = 0; rt < 4; ++rt)
        #pragma unroll
        for (int ki = 0; ki < 8; ++ki)
            areg[rt][ki] = *(const half8*)(
                Atile + (size_t)((ki * 2 + lh) * 128 + rt * 32 + ln31) * 8);

    // b2 slice -> LDS (keeps the loop's vmcnt domain staging-only).
    int s = blockIdx.y;
    for (int j = tid; j < Mslice; j += 256)
        b2sh[j] = b2h[s * Mslice + j];

    half2v minacc[4][8];
    const half_t HMAX = (half_t)65504.f;
    #pragma unroll
    for (int rt = 0; rt < 4; ++rt)
        #pragma unroll
        for (int i = 0; i < 8; ++i) { minacc[rt][i][0] = HMAX; minacc[rt][i][1] = HMAX; }

    int iters = Mslice >> 7;   // 16
    const half_t* Bbase = Bws + (size_t)s * iters * TILE_ELEMS;

    __syncthreads();   // b2sh visible; all vm/lgkm drained -> counted waits exact

    half_t* buf0 = &slices[wc][0][0];
    half_t* buf1 = &slices[wc][1][0];

    // Prologue: 2-deep per-wave prefetch (outstanding = 16 loads).
    stage_slice(Bbase,              buf0, wc, lane);
    stage_slice(Bbase + TILE_ELEMS, buf1, wc, lane);

    for (int t = 0; t < iters - 1; ++t)
        gemm_iter<8>(t, iters, wc, lane, ln31, lh, Bbase, buf0, buf1, b2sh, areg, minacc);
    gemm_iter<0>(iters - 1, iters, wc, lane, ln31, lh, Bbase, buf0, buf1, b2sh, areg, minacc);

    // Packed cross-lane min over the 32 column-lanes, then unpack + write.
    // C/D row of element r: (r&3) + 8*(r>>2) + 4*lh; packed pair = r=2i,2i+1.
    #pragma unroll
    for (int rt = 0; rt < 4; ++rt)
        #pragma unroll
        for (int i = 0; i < 8; ++i) {
            int m = __builtin_bit_cast(int, minacc[rt][i]);
            #pragma unroll
            for (int x = 1; x < 32; x <<= 1) {
                int o = __shfl_xor(m, x, 64);
                m = __builtin_bit_cast(int,
                        h2min(__builtin_bit_cast(half2v, m),
                              __builtin_bit_cast(half2v, o)));
            }
            if (ln31 == 0) {
                half2v mv = __builtin_bit_cast(half2v, m);
                int r0 = 2 * i, r1 = 2 * i + 1;
                int rowb = blockIdx.x * 128 + rt * 32 + 4 * lh;
                int row0 = rowb + (r0 & 3) + 8 * (r0 >> 2);
                int row1 = rowb + (r1 & 3) + 8 * (r1 >> 2);
                Pmin[(size_t)row0 * 16 + s * 4 + wc] = (float)mv[0];
                Pmin[(size_t)row1 * 16 + s * 4 + wc] = (float)mv[1];
            }
        }
}

// One thread per row: min of 16 partials, d2 = a2 + 2*min, sqrt/shift/clamp.
__global__ __launch_bounds__(256) void final_kernel(
    const float* __restrict__ a2, const float* __restrict__ Pmin,
    float* __restrict__ out)
{
    int row = blockIdx.x * 256 + threadIdx.x;
    const float4* pp = (const float4*)(Pmin + (size_t)row * 16);
    float4 p0 = pp[0];
    float4 p1 = pp[1];
    float4 p2 = pp[2];
    float4 p3 = pp[3];
    float q0 = fminf(fminf(p0.x, p0.y), fminf(p0.z, p0.w));
    float q1 = fminf(fminf(p1.x, p1.y), fminf(p1.z, p1.w));
    float q2 = fminf(fminf(p2.x, p2.y), fminf(p2.z, p2.w));
    float q3 = fminf(fminf(p3.x, p3.y), fminf(p3.z, p3.w));
    float p  = fminf(fminf(q0, q1), fminf(q2, q3));
    float d2 = a2[row] + 2.f * p;
    float d  = sqrtf(fmaxf(d2, 0.f));
    out[row] = fmaxf(d - 0.1f, 0.f);
}

extern "C" void kernel_launch(void* const* d_in, const int* in_sizes, int n_in,
                              void* d_out, int out_size, void* d_ws, size_t ws_size,
                              hipStream_t stream)
{
    const float* x    = (const float*)d_in[0];
    const float* self = (const float*)d_in[1];
    float* out        = (float*)d_out;

    int N = in_sizes[0] / 128;   // 16384
    int M = in_sizes[1] / 128;   // 8192
    int Atiles = N / 128;        // 128
    int Btiles = M / 128;        // 64

    char* w      = (char*)d_ws;
    half_t* Aws  = (half_t*)w;
    half_t* Bws  = Aws + (size_t)N * 128;
    float*  b2h  = (float*)(w + (size_t)(N + M) * 128 * 2);
    float*  Pmin = b2h + M;
    float*  a2   = Pmin + (size_t)N * 16;
    // ws: 4 MB + 2 MB + 32 KB + 1 MB + 64 KB ≈ 7.3 MB

    prep_kernel<<<Atiles + Btiles, 256, 0, stream>>>(x, self, Aws, Bws, b2h, a2, Atiles);

    int Mslice = M / 4;          // 2048 -> 16 tile-iterations
    dim3 grid(N / 128, 4);       // 512 blocks = 2/CU, 4 waves each
    min_gemm_kernel<<<grid, 256, 0, stream>>>(Aws, Bws, b2h, Pmin, Mslice);

    final_kernel<<<N / 256, 256, 0, stream>>>(a2, Pmin, out);
}

// Round 7
// 102.268 us; speedup vs baseline: 1.0797x; 1.0797x over previous
//
#include <hip/hip_runtime.h>

// NegativeSelection: score[i] = max(min_j ||x_i - s_j|| - 0.1, 0)
// N=16384, M=8192, D=128, fp32 in/out.
//
// d2 = a2 + b2 - 2*dot. dot via fp16 MFMA (32x32x16), A pre-negated so
// acc = C_init(b2/2) + (-x)·s = b2/2 - dot; min over j tracked per row.
// final: d2 = a2 + 2*min, score = max(sqrt(max(d2,0)) - 0.1, 0).
//
// This revision: OCCUPANCY. Every prior structure ran exactly 2 waves/SIMD
// and plateaued at MfmaUtil 26-31% (= the 13.7 us matrix floor inside a
// 42-50 us wall). This version fits 4 blocks/CU x 4 waves = 4 waves/SIMD:
//   - block = 128 rows x 64-col B sub-tiles, 4 waves of 64x32 (dup=2);
//   - VGPR <= 128 (launch_bounds(256,4)): areg 64 + acc 32 + f16-packed
//     min 16 + JIT B-frag reads (live ~8);
//   - LDS 36 KB: 2 x 16 KB B double-buffer + 4 KB b2 slice;
//   - stage(t+1) issued right after the single per-iter barrier; own-wave
//     vmcnt(0) + s_barrier at iter top (stage had a full compute phase to
//     land, so the wait is cheap; depth-1 dbuf has nothing for a counted
//     wait to preserve).
//
// ws: Aws fp16 [N*128] (4 MB, [k8][row][8], NEGATED), Bws fp16 [M*128] (2 MB),
//     b2h f32 [M], Pmin f32 [N*16], a2 f32 [N]  -> ~7.3 MB.

using half_t = _Float16;
typedef _Float16 half8 __attribute__((ext_vector_type(8)));
typedef _Float16 half2v __attribute__((ext_vector_type(2)));
typedef float floatx16 __attribute__((ext_vector_type(16)));

#define TILE_ELEMS (128 * 128)   // one 128x128 fp16 tile = 32 KB

__device__ __forceinline__ void async_load16(const void* g, void* l) {
    __builtin_amdgcn_global_load_lds(
        (const __attribute__((address_space(1))) void*)g,
        (__attribute__((address_space(3))) void*)l, 16, 0, 0);
}

// 256 threads stage one 16 KB 64-col sub-tile (layout [k8:16][col:64][8]):
// 4 chunks of 16 B per thread, LDS dest linear (wave-uniform base + lane*16).
// Global: chunk c=(k8*64+col) -> element (k8*128+col)*8 past base.
__device__ __forceinline__ void stage_tile64(const half_t* __restrict__ base,
                                             half_t* __restrict__ dst, int tid) {
    #pragma unroll
    for (int j = 0; j < 4; ++j) {
        int c = j * 256 + tid;
        const half_t* src = base + (size_t)(c + (c >> 6) * 64) * 8;
        async_load16(src, dst + (size_t)c * 8);
    }
}

__device__ __forceinline__ half2v h2min(half2v a, half2v b) {
    return __builtin_elementwise_min(a, b);   // v_pk_min_f16
}

__device__ __forceinline__ half2v pkrtz(float lo, float hi) {
    auto t = __builtin_amdgcn_cvt_pkrtz(lo, hi);
    return __builtin_bit_cast(half2v, t);
}

// One block per 128x128 tile. fp32 -> fp16 tiled layout [k8][row][8]
// (chunk c = k8*128+row stored at element c*8). A negated.
// B tiles: b2h = 0.5*sum(row^2). A tiles: a2 = sum(row^2).
__global__ __launch_bounds__(256) void prep_kernel(
    const float* __restrict__ x, const float* __restrict__ self,
    half_t* __restrict__ Aws, half_t* __restrict__ Bws,
    float* __restrict__ b2h, float* __restrict__ a2, int Atiles)
{
    __shared__ float part[256];
    int tile = blockIdx.x;
    int tid  = threadIdx.x;
    bool isB = tile >= Atiles;
    int bt   = tile - Atiles;
    const float* src = isB ? (self + (size_t)bt * TILE_ELEMS)
                           : (x    + (size_t)tile * TILE_ELEMS);
    half_t* dst = isB ? (Bws + (size_t)bt * TILE_ELEMS)
                      : (Aws + (size_t)tile * TILE_ELEMS);
    float sgn = isB ? 1.f : -1.f;

    int rowt = tid & 127;
    int k8b  = tid >> 7;
    float ss = 0.f;
    #pragma unroll
    for (int i = 0; i < 8; ++i) {
        int k8 = i * 2 + k8b;
        const float4* p = (const float4*)(src + rowt * 128 + k8 * 8);
        float4 f0 = p[0];
        float4 f1 = p[1];
        half8 h;
        h[0] = (half_t)(sgn * f0.x); h[1] = (half_t)(sgn * f0.y);
        h[2] = (half_t)(sgn * f0.z); h[3] = (half_t)(sgn * f0.w);
        h[4] = (half_t)(sgn * f1.x); h[5] = (half_t)(sgn * f1.y);
        h[6] = (half_t)(sgn * f1.z); h[7] = (half_t)(sgn * f1.w);
        *(half8*)(dst + (size_t)(i * 256 + tid) * 8) = h;
        ss += f0.x*f0.x + f0.y*f0.y + f0.z*f0.z + f0.w*f0.w;
        ss += f1.x*f1.x + f1.y*f1.y + f1.z*f1.z + f1.w*f1.w;
    }
    part[tid] = ss;
    __syncthreads();
    if (tid < 128) {
        float tot = part[tid] + part[tid + 128];
        if (isB) b2h[bt * 128 + tid] = 0.5f * tot;
        else     a2[tile * 128 + tid] = tot;
    }
}

// Grid: (N/128 row-blocks, 8 M-slices of 1024). 256 threads = 4 waves in
// 2x2 (wr: 64-row group, wc: 32-col group). Per iter one 64-col B sub-tile.
// 36 KB LDS + <=128 VGPR -> 4 blocks/CU = 4 waves/SIMD.
__global__ __launch_bounds__(256, 4) void min_gemm_kernel(
    const half_t* __restrict__ Aws, const half_t* __restrict__ Bws,
    const float* __restrict__ b2h, float* __restrict__ Pmin, int Mslice)
{
    __shared__ half_t bufs[2][16 * 64 * 8];   // 2 x 16 KB, [k8:16][col:64][8]
    __shared__ float  b2sh[1024];             // 4 KB (Mslice = 1024)

    int tid  = threadIdx.x;
    int lane = tid & 63;
    int wid  = tid >> 6;
    int wr   = wid >> 1;          // 0..1 : 64-row group
    int wc   = wid & 1;           // 0..1 : 32-col group
    int ln31 = lane & 31, lh = lane >> 5;

    // A fragments: rows bx*128 + wr*64 + rt*32 + ln31, full K (64 VGPR).
    const half_t* Atile = Aws + (size_t)blockIdx.x * TILE_ELEMS;
    half8 areg[2][8];
    #pragma unroll
    for (int rt = 0; rt < 2; ++rt)
        #pragma unroll
        for (int ki = 0; ki < 8; ++ki)
            areg[rt][ki] = *(const half8*)(
                Atile + (size_t)((ki * 2 + lh) * 128 + wr * 64 + rt * 32 + ln31) * 8);

    // b2 slice -> LDS.
    int s = blockIdx.y;
    for (int j = tid; j < 1024; j += 256)
        b2sh[j] = b2h[s * 1024 + j];

    half2v minacc[2][8];
    const half_t HMAX = (half_t)65504.f;
    #pragma unroll
    for (int rt = 0; rt < 2; ++rt)
        #pragma unroll
        for (int i = 0; i < 8; ++i) { minacc[rt][i][0] = HMAX; minacc[rt][i][1] = HMAX; }

    int iters = Mslice >> 6;   // 16 sub-tiles of 64 cols
    // Source base for iter it: 128-tile (s*8 + it/2), row offset (it&1)*64.
    const half_t* Bslice = Bws + (size_t)s * 8 * TILE_ELEMS;

    // Prologue: stage tile 0 (its wait happens at the t=0 loop head).
    stage_tile64(Bslice, &bufs[0][0], tid);

    for (int t = 0; t < iters; ++t) {
        asm volatile("s_waitcnt vmcnt(0)" ::: "memory");  // own stage(t) landed
        __builtin_amdgcn_s_barrier();   // all waves' stage(t) landed;
                                        // prior reads of bufs[(t+1)&1] done
        __builtin_amdgcn_sched_barrier(0);

        if (t + 1 < iters) {
            const half_t* nb = Bslice + (size_t)((t + 1) >> 1) * TILE_ELEMS
                             + (size_t)(((t + 1) & 1) * 64) * 8;
            stage_tile64(nb, &bufs[(t + 1) & 1][0], tid);
        }

        const half_t* Bs = &bufs[t & 1][0];
        float b2v = b2sh[t * 64 + wc * 32 + ln31];

        floatx16 acc0, acc1;
        #pragma unroll
        for (int r = 0; r < 16; ++r) { acc0[r] = b2v; acc1[r] = b2v; }

        #pragma unroll
        for (int ki = 0; ki < 8; ++ki) {
            half8 bf = *(const half8*)(Bs + (size_t)((ki * 2 + lh) * 64 + wc * 32 + ln31) * 8);
            acc0 = __builtin_amdgcn_mfma_f32_32x32x16_f16(areg[0][ki], bf, acc0, 0, 0, 0);
            acc1 = __builtin_amdgcn_mfma_f32_32x32x16_f16(areg[1][ki], bf, acc1, 0, 0, 0);
        }

        // acc = b2/2 - dot; fold into packed-f16 running min.
        #pragma unroll
        for (int i = 0; i < 8; ++i) {
            minacc[0][i] = h2min(minacc[0][i], pkrtz(acc0[2 * i], acc0[2 * i + 1]));
            minacc[1][i] = h2min(minacc[1][i], pkrtz(acc1[2 * i], acc1[2 * i + 1]));
        }
    }

    // Packed cross-lane min over the 32 column-lanes, then unpack + write.
    // C/D row of element r: (r&3) + 8*(r>>2) + 4*lh; packed pair = r=2i,2i+1.
    #pragma unroll
    for (int rt = 0; rt < 2; ++rt)
        #pragma unroll
        for (int i = 0; i < 8; ++i) {
            int m = __builtin_bit_cast(int, minacc[rt][i]);
            #pragma unroll
            for (int x = 1; x < 32; x <<= 1) {
                int o = __shfl_xor(m, x, 64);
                m = __builtin_bit_cast(int,
                        h2min(__builtin_bit_cast(half2v, m),
                              __builtin_bit_cast(half2v, o)));
            }
            if (ln31 == 0) {
                half2v mv = __builtin_bit_cast(half2v, m);
                int r0 = 2 * i, r1 = 2 * i + 1;
                int rowb = blockIdx.x * 128 + wr * 64 + rt * 32 + 4 * lh;
                int row0 = rowb + (r0 & 3) + 8 * (r0 >> 2);
                int row1 = rowb + (r1 & 3) + 8 * (r1 >> 2);
                Pmin[(size_t)row0 * 16 + s * 2 + wc] = (float)mv[0];
                Pmin[(size_t)row1 * 16 + s * 2 + wc] = (float)mv[1];
            }
        }
}

// One thread per row: min of 16 partials, d2 = a2 + 2*min, sqrt/shift/clamp.
__global__ __launch_bounds__(256) void final_kernel(
    const float* __restrict__ a2, const float* __restrict__ Pmin,
    float* __restrict__ out)
{
    int row = blockIdx.x * 256 + threadIdx.x;
    const float4* pp = (const float4*)(Pmin + (size_t)row * 16);
    float4 p0 = pp[0];
    float4 p1 = pp[1];
    float4 p2 = pp[2];
    float4 p3 = pp[3];
    float q0 = fminf(fminf(p0.x, p0.y), fminf(p0.z, p0.w));
    float q1 = fminf(fminf(p1.x, p1.y), fminf(p1.z, p1.w));
    float q2 = fminf(fminf(p2.x, p2.y), fminf(p2.z, p2.w));
    float q3 = fminf(fminf(p3.x, p3.y), fminf(p3.z, p3.w));
    float p  = fminf(fminf(q0, q1), fminf(q2, q3));
    float d2 = a2[row] + 2.f * p;
    float d  = sqrtf(fmaxf(d2, 0.f));
    out[row] = fmaxf(d - 0.1f, 0.f);
}

extern "C" void kernel_launch(void* const* d_in, const int* in_sizes, int n_in,
                              void* d_out, int out_size, void* d_ws, size_t ws_size,
                              hipStream_t stream)
{
    const float* x    = (const float*)d_in[0];
    const float* self = (const float*)d_in[1];
    float* out        = (float*)d_out;

    int N = in_sizes[0] / 128;   // 16384
    int M = in_sizes[1] / 128;   // 8192
    int Atiles = N / 128;        // 128
    int Btiles = M / 128;        // 64

    char* w      = (char*)d_ws;
    half_t* Aws  = (half_t*)w;
    half_t* Bws  = Aws + (size_t)N * 128;
    float*  b2h  = (float*)(w + (size_t)(N + M) * 128 * 2);
    float*  Pmin = b2h + M;
    float*  a2   = Pmin + (size_t)N * 16;
    // ws: 4 MB + 2 MB + 32 KB + 1 MB + 64 KB ≈ 7.3 MB

    prep_kernel<<<Atiles + Btiles, 256, 0, stream>>>(x, self, Aws, Bws, b2h, a2, Atiles);

    int Mslice = M / 8;          // 1024 cols -> 16 sub-tiles of 64
    dim3 grid(N / 128, 8);       // 1024 blocks = 4/CU, 4 waves each
    min_gemm_kernel<<<grid, 256, 0, stream>>>(Aws, Bws, b2h, Pmin, Mslice);

    final_kernel<<<N / 256, 256, 0, stream>>>(a2, Pmin, out);
}